// Round 14
// baseline (302.596 us; speedup 1.0000x reference)
//
#include <hip/hip_runtime.h>

// FullNN: per-atom MLP (FEAT=64 -> tanh(HID=64) -> 1) + segment-sum over 32768 structs.
// Round 14: the 11-round invariant (~3.8 TB/s delivered, occupancy-independent from
// 20%-66%) is finally explained by LINE UTILIZATION: fragment-layout lane addressing
// (stride 256B) uses 32B per 128B line per instruction; cross-instruction line reuse
// dies in L1 (16 waves x 4KB >> 32KB) -> lines re-fetched up to 4x -> ~6 B/cyc/CU
// vs copy's 10.2. Fix: lane-LINEAR loads (lane l reads tile + j*1024 + l*16; every
// instruction = 1KB contiguous, full 128B lines, thrash-immune) + wave-private LDS
// redistribute with XOR chunk swizzle (2-way conflicts = free, m136). Pure C: no
// asm, no barriers -- compiler emits counted vmcnt (proven round 13 / m97).
//
// LDS chunk map (chunk = 16B): logical (row, j) -> physical row*16 + (j ^ (row&7)).
//   write (linear instr j): lane -> chunk j*64+lane = (row=j*4+kg, jj=col)
//   read  (fragment):       lane (col,kg) reads rows col, j = kg*2+d / 8+kg*2+d
// MFMA mfma_f32_16x16x32_bf16, swapped H^T = W1^T @ x^T (learn_hip m89/m97):
//   A: row=lane&15, k=(lane>>4)*8+i -> W1^T frag (registers)
//   B: col=lane&15 (= atom), k=(lane>>4)*8+i -> x^T frag (via LDS redistribute)
//   D: col=lane&15 (= atom), j=16t+kg*4+r    -> in-lane W2 reduce, 2 shfls

typedef __attribute__((ext_vector_type(8))) short bf16x8;
typedef __attribute__((ext_vector_type(4))) float f32x4;

struct ElemPtrs {
    const float* x;
    const int*   idx;
    const float* W1;
    const float* b1;
    const float* W2;
    const float* b2;
};
struct Params {
    ElemPtrs e[3];
    int n_tiles;   // atoms / 16
};

__device__ __forceinline__ short f2bf(float f) {
    __bf16 h = (__bf16)f;           // hardware RNE; pairs into v_cvt_pk_bf16_f32
    return __builtin_bit_cast(short, h);
}

__device__ __forceinline__ float fast_tanh(float v) {
    v = __builtin_amdgcn_fmed3f(v, -10.0f, 10.0f);
    float t = __builtin_amdgcn_exp2f(v * 2.8853900817779268f); // 2^(2v*log2 e)
    return (t - 1.0f) * __builtin_amdgcn_rcpf(t + 1.0f);
}

__global__ __launch_bounds__(256, 4) void atom_mlp(Params p, float* __restrict__ out)
{
    const ElemPtrs ep = p.e[blockIdx.y];   // uniform index -> scalar code

    // wave-private redistribute buffers: 4 waves x 256 chunks x 16B = 16 KB
    __shared__ f32x4 xbuf[4][256];

    const int tid  = threadIdx.x;
    const int wv   = tid >> 6;
    const int lane = tid & 63;
    const int col  = lane & 15;    // atom within tile
    const int kg   = lane >> 4;    // k-group
    f32x4* __restrict__ buf = xbuf[wv];

    // ---- persistent W1^T A-fragments (32 VGPR) ----
    bf16x8 Wf[2][4];
    #pragma unroll
    for (int s = 0; s < 2; ++s)
        #pragma unroll
        for (int t = 0; t < 4; ++t)
            #pragma unroll
            for (int i = 0; i < 8; ++i)
                Wf[s][t][i] = f2bf(ep.W1[(s * 32 + kg * 8 + i) * 64 + 16 * t + col]);

    // per-lane b1 (MFMA C-init) and W2, j = 16t + kg*4 + r
    f32x4 b1c[4], w2c[4];
    #pragma unroll
    for (int t = 0; t < 4; ++t)
        #pragma unroll
        for (int r = 0; r < 4; ++r) {
            b1c[t][r] = ep.b1[16 * t + kg * 4 + r];
            w2c[t][r] = ep.W2[16 * t + kg * 4 + r];
        }
    const float b2v = ep.b2[0];

    // ---- LDS chunk indices (loop-invariant scalars) ----
    // write side: instr j -> physical chunk (j*4+kg)*16 + (col ^ ((j*4+kg)&7))
    const int wc0 = (0 * 4 + kg) * 16 + (col ^ ((0 * 4 + kg) & 7));
    const int wc1 = (1 * 4 + kg) * 16 + (col ^ ((1 * 4 + kg) & 7));
    const int wc2 = (2 * 4 + kg) * 16 + (col ^ ((2 * 4 + kg) & 7));
    const int wc3 = (3 * 4 + kg) * 16 + (col ^ ((3 * 4 + kg) & 7));
    // read side: row col, logical j -> physical col*16 + (j ^ (col&7))
    const int rc0 = col * 16 + ((kg * 2 + 0) ^ (col & 7));
    const int rc1 = col * 16 + ((kg * 2 + 1) ^ (col & 7));
    const int rc2 = col * 16 + ((8 + kg * 2 + 0) ^ (col & 7));
    const int rc3 = col * 16 + ((8 + kg * 2 + 1) ^ (col & 7));

    const int nt  = p.n_tiles;
    const int wid = (blockIdx.x * 256 + tid) >> 6;
    const int nw  = (gridDim.x * 256) >> 6;

    int tCur = wid;
    if (tCur >= nt) return;                // wave-uniform

    const char* __restrict__ xb = (const char*)ep.x;
    const unsigned loff = (unsigned)(lane * 16);   // lane-LINEAR: full-line loads

    f32x4 lA0, lA1, lA2, lA3, lB0, lB1, lB2, lB3;
    int iaA = 0, iaB = 0;

    // prologue: fill slot A (lane-linear, 4 x 1KB-contiguous instructions)
    {
        const char* tb = xb + (size_t)tCur * 4096;
        lA0 = *reinterpret_cast<const f32x4*>(tb + loff);
        lA1 = *reinterpret_cast<const f32x4*>(tb + 1024 + loff);
        lA2 = *reinterpret_cast<const f32x4*>(tb + 2048 + loff);
        lA3 = *reinterpret_cast<const f32x4*>(tb + 3072 + loff);
        iaA = ep.idx[tCur * 16 + col];
    }

    // body: refill OTHER slot from t+nw (stays in flight across the counted
    // vmcnt that the ds_writes of CUR require), redistribute CUR through LDS,
    // read fragments, convert, 8 MFMA, tanh epilogue, 2 shfl, atomic.
#define BODY(CUR, NXT)                                                            \
    {                                                                             \
        const int tn = tCur + nw;                                                 \
        hN = (tn < nt);                        /* wave-uniform */                 \
        if (hN) {                                                                 \
            const char* tb = xb + (size_t)tn * 4096;                              \
            l##NXT##0 = *reinterpret_cast<const f32x4*>(tb + loff);               \
            l##NXT##1 = *reinterpret_cast<const f32x4*>(tb + 1024 + loff);        \
            l##NXT##2 = *reinterpret_cast<const f32x4*>(tb + 2048 + loff);        \
            l##NXT##3 = *reinterpret_cast<const f32x4*>(tb + 3072 + loff);        \
            ia##NXT   = ep.idx[tn * 16 + col];                                    \
        }                                                                         \
        buf[wc0] = l##CUR##0;                                                     \
        buf[wc1] = l##CUR##1;                                                     \
        buf[wc2] = l##CUR##2;                                                     \
        buf[wc3] = l##CUR##3;                                                     \
        const f32x4 f0 = buf[rc0];                                                \
        const f32x4 f1 = buf[rc1];                                                \
        const f32x4 f2 = buf[rc2];                                                \
        const f32x4 f3 = buf[rc3];                                                \
        bf16x8 X0, X1;                                                            \
        X0[0]=f2bf(f0[0]); X0[1]=f2bf(f0[1]); X0[2]=f2bf(f0[2]); X0[3]=f2bf(f0[3]); \
        X0[4]=f2bf(f1[0]); X0[5]=f2bf(f1[1]); X0[6]=f2bf(f1[2]); X0[7]=f2bf(f1[3]); \
        X1[0]=f2bf(f2[0]); X1[1]=f2bf(f2[1]); X1[2]=f2bf(f2[2]); X1[3]=f2bf(f2[3]); \
        X1[4]=f2bf(f3[0]); X1[5]=f2bf(f3[1]); X1[6]=f2bf(f3[2]); X1[7]=f2bf(f3[3]); \
        f32x4 a0 = __builtin_amdgcn_mfma_f32_16x16x32_bf16(Wf[0][0], X0, b1c[0], 0, 0, 0); \
        f32x4 a1 = __builtin_amdgcn_mfma_f32_16x16x32_bf16(Wf[0][1], X0, b1c[1], 0, 0, 0); \
        f32x4 a2 = __builtin_amdgcn_mfma_f32_16x16x32_bf16(Wf[0][2], X0, b1c[2], 0, 0, 0); \
        f32x4 a3 = __builtin_amdgcn_mfma_f32_16x16x32_bf16(Wf[0][3], X0, b1c[3], 0, 0, 0); \
        a0 = __builtin_amdgcn_mfma_f32_16x16x32_bf16(Wf[1][0], X1, a0, 0, 0, 0);  \
        a1 = __builtin_amdgcn_mfma_f32_16x16x32_bf16(Wf[1][1], X1, a1, 0, 0, 0);  \
        a2 = __builtin_amdgcn_mfma_f32_16x16x32_bf16(Wf[1][2], X1, a2, 0, 0, 0);  \
        a3 = __builtin_amdgcn_mfma_f32_16x16x32_bf16(Wf[1][3], X1, a3, 0, 0, 0);  \
        float ev;                                                                 \
        ev  = fast_tanh(a0[0]) * w2c[0][0];                                       \
        ev += fast_tanh(a0[1]) * w2c[0][1];                                       \
        ev += fast_tanh(a0[2]) * w2c[0][2];                                       \
        ev += fast_tanh(a0[3]) * w2c[0][3];                                       \
        ev += fast_tanh(a1[0]) * w2c[1][0];                                       \
        ev += fast_tanh(a1[1]) * w2c[1][1];                                       \
        ev += fast_tanh(a1[2]) * w2c[1][2];                                       \
        ev += fast_tanh(a1[3]) * w2c[1][3];                                       \
        ev += fast_tanh(a2[0]) * w2c[2][0];                                       \
        ev += fast_tanh(a2[1]) * w2c[2][1];                                       \
        ev += fast_tanh(a2[2]) * w2c[2][2];                                       \
        ev += fast_tanh(a2[3]) * w2c[2][3];                                       \
        ev += fast_tanh(a3[0]) * w2c[3][0];                                       \
        ev += fast_tanh(a3[1]) * w2c[3][1];                                       \
        ev += fast_tanh(a3[2]) * w2c[3][2];                                       \
        ev += fast_tanh(a3[3]) * w2c[3][3];                                       \
        ev += __shfl_xor(ev, 16);                                                 \
        ev += __shfl_xor(ev, 32);                                                 \
        if (lane < 16) atomicAdd(&out[ia##CUR], ev + b2v);                        \
        tCur = tn;                                                                \
    }

    bool hN;
    while (true) {
        BODY(A, B);
        if (!hN) break;
        BODY(B, A);
        if (!hN) break;
    }
#undef BODY
}

extern "C" void kernel_launch(void* const* d_in, const int* in_sizes, int n_in,
                              void* d_out, int out_size, void* d_ws, size_t ws_size,
                              hipStream_t stream) {
    Params p;
    for (int e = 0; e < 3; ++e) {
        p.e[e].x   = (const float*)d_in[6 * e + 0];
        p.e[e].idx = (const int*)  d_in[6 * e + 1];
        p.e[e].W1  = (const float*)d_in[6 * e + 2];
        p.e[e].b1  = (const float*)d_in[6 * e + 3];
        p.e[e].W2  = (const float*)d_in[6 * e + 4];
        p.e[e].b2  = (const float*)d_in[6 * e + 5];
    }
    const int n_atoms = in_sizes[0] / 64;
    p.n_tiles = n_atoms / 16;   // 62,500

    float* out = (float*)d_out;
    // d_out is poisoned (0xAA) before timing and NOT re-zeroed between replays.
    hipMemsetAsync(out, 0, (size_t)out_size * sizeof(float), stream);

    dim3 grid(683, 3);   // 2049 blocks; grid-stride; residency set by VGPR/LDS
    atom_mlp<<<grid, 256, 0, stream>>>(p, out);
}

// Round 15
// 297.053 us; speedup vs baseline: 1.0187x; 1.0187x over previous
//
#include <hip/hip_runtime.h>

// FullNN: per-atom MLP (FEAT=64 -> tanh(HID=64) -> 1) + segment-sum over 32768 structs.
// Round 15: INSTRUMENTED ROUND. Rounds 3-14 falsified latency/concurrency/line-
// utilization theories; the surviving empirical law is dur = FETCH_SIZE / 1.78 TB/s
// (R13: 381MB->217us; R14: 555MB->316us), occupancy-invariant 20%-66%. The never-
// measured discriminator: the x-stream's standalone platform rate. This round runs
//   1) bw_probe: exact fragment-pattern x+idx reads, max TLP (8 waves/SIMD, ~20
//      VGPR, no LDS/MFMA/atomics), asm-sink keeps loads live (rule #17).
//   2) atom_mlp: round-10 kernel verbatim (best steady 204us) for correctness +
//      a clean compute-side rocprof row.
// Pre-committed: probe <=135us -> interference, go warp-specialized; probe ~205us
// -> fused kernel is AT the pattern ceiling -> declare roofline.

typedef __attribute__((ext_vector_type(8))) short bf16x8;
typedef __attribute__((ext_vector_type(4))) float f32x4;

struct ElemPtrs {
    const float* x;
    const int*   idx;
    const float* W1;
    const float* b1;
    const float* W2;
    const float* b2;
};
struct Params {
    ElemPtrs e[3];
    int n_tiles;   // atoms / 16
};

__device__ __forceinline__ short f2bf(float f) {
    __bf16 h = (__bf16)f;           // hardware RNE; pairs into v_cvt_pk_bf16_f32
    return __builtin_bit_cast(short, h);
}

__device__ __forceinline__ float fast_tanh(float v) {
    v = __builtin_amdgcn_fmed3f(v, -10.0f, 10.0f);
    float t = __builtin_amdgcn_exp2f(v * 2.8853900817779268f); // 2^(2v*log2 e)
    return (t - 1.0f) * __builtin_amdgcn_rcpf(t + 1.0f);
}

// ---------------- kernel 1: pure-read probe of the x stream ----------------
__global__ __launch_bounds__(256, 8) void bw_probe(Params p)
{
    const ElemPtrs ep = p.e[blockIdx.y];
    const int tid  = threadIdx.x;
    const int lane = tid & 63;
    const int col  = lane & 15;
    const int kg   = lane >> 4;

    const int wid = (blockIdx.x * 256 + tid) >> 6;
    const int nw  = (gridDim.x * 256) >> 6;
    const size_t xoff = (size_t)col * 64 + (size_t)kg * 8;

    for (int t = wid; t < p.n_tiles; t += nw) {
        const float* xp = ep.x + (size_t)t * 1024 + xoff;
        f32x4 a = *reinterpret_cast<const f32x4*>(xp);
        f32x4 b = *reinterpret_cast<const f32x4*>(xp + 4);
        f32x4 c = *reinterpret_cast<const f32x4*>(xp + 32);
        f32x4 d = *reinterpret_cast<const f32x4*>(xp + 36);
        int   i = ep.idx[t * 16 + col];
        // keep loads live without consuming them (rule #17)
        asm volatile("" :: "v"(a), "v"(b), "v"(c), "v"(d), "v"(i));
    }
}

// ---------------- kernel 2: round-10 compute kernel, verbatim ----------------
__global__ __launch_bounds__(256, 4) void atom_mlp(Params p, float* __restrict__ out)
{
    const ElemPtrs ep = p.e[blockIdx.y];   // uniform index -> scalar code

    // W1^T fragments, shared by the block's 4 waves: [frag fid=s*4+t][lane] x 16B
    __shared__ bf16x8 Wlds[8][64];

    const int tid  = threadIdx.x;
    const int lane = tid & 63;
    const int col  = lane & 15;    // atom within tile
    const int kg   = lane >> 4;    // k-group

    // ---- cooperative stage of W1^T fragments ----
    {
        const int wv = tid >> 6;
        #pragma unroll
        for (int q = 0; q < 2; ++q) {
            const int fid = wv * 2 + q;
            const int s = fid >> 2, t = fid & 3;
            bf16x8 w;
            #pragma unroll
            for (int i = 0; i < 8; ++i)
                w[i] = f2bf(ep.W1[(s * 32 + kg * 8 + i) * 64 + 16 * t + col]);
            Wlds[fid][lane] = w;
        }
    }

    // per-lane b1 (MFMA C-init) and W2, j = 16t + kg*4 + r
    f32x4 b1c[4], w2c[4];
    #pragma unroll
    for (int t = 0; t < 4; ++t)
        #pragma unroll
        for (int r = 0; r < 4; ++r) {
            b1c[t][r] = ep.b1[16 * t + kg * 4 + r];
            w2c[t][r] = ep.W2[16 * t + kg * 4 + r];
        }
    const float b2v = ep.b2[0];

    __syncthreads();

    // 32-bit LDS byte address of this lane's frag 0 (frag fid at +fid*1024)
    typedef __attribute__((address_space(3))) const void* as3cv;
    const unsigned waddr = (unsigned)(size_t)(as3cv)&Wlds[0][lane];

    const int wid    = (blockIdx.x * 256 + tid) >> 6;
    const int nwaves = (gridDim.x * 256) >> 6;
    const size_t xoff = (size_t)col * 64 + (size_t)kg * 8;

    for (int tile = wid; tile < p.n_tiles; tile += nwaves) {
        const float* xp = ep.x + (size_t)tile * 1024 + xoff;
        const float4 c0 = *reinterpret_cast<const float4*>(xp);
        const float4 c1 = *reinterpret_cast<const float4*>(xp + 4);
        const float4 c2 = *reinterpret_cast<const float4*>(xp + 32);
        const float4 c3 = *reinterpret_cast<const float4*>(xp + 36);
        const int ia = ep.idx[tile * 16 + col];

        bf16x8 X0, X1;
        X0[0]=f2bf(c0.x); X0[1]=f2bf(c0.y); X0[2]=f2bf(c0.z); X0[3]=f2bf(c0.w);
        X0[4]=f2bf(c1.x); X0[5]=f2bf(c1.y); X0[6]=f2bf(c1.z); X0[7]=f2bf(c1.w);
        X1[0]=f2bf(c2.x); X1[1]=f2bf(c2.y); X1[2]=f2bf(c2.z); X1[3]=f2bf(c2.w);
        X1[4]=f2bf(c3.x); X1[5]=f2bf(c3.y); X1[6]=f2bf(c3.z); X1[7]=f2bf(c3.w);

        // ---- frag group 0 (fids 0..3) from LDS, then 4 MFMAs on X0 ----
        bf16x8 w0, w1, w2, w3;
        asm volatile("ds_read_b128 %0, %1 offset:0"    : "=v"(w0) : "v"(waddr));
        asm volatile("ds_read_b128 %0, %1 offset:1024" : "=v"(w1) : "v"(waddr));
        asm volatile("ds_read_b128 %0, %1 offset:2048" : "=v"(w2) : "v"(waddr));
        asm volatile("ds_read_b128 %0, %1 offset:3072" : "=v"(w3) : "v"(waddr));
        asm volatile("s_waitcnt lgkmcnt(0)" ::: "memory");
        __builtin_amdgcn_sched_barrier(0);

        f32x4 a0 = __builtin_amdgcn_mfma_f32_16x16x32_bf16(w0, X0, b1c[0], 0, 0, 0);
        f32x4 a1 = __builtin_amdgcn_mfma_f32_16x16x32_bf16(w1, X0, b1c[1], 0, 0, 0);
        f32x4 a2 = __builtin_amdgcn_mfma_f32_16x16x32_bf16(w2, X0, b1c[2], 0, 0, 0);
        f32x4 a3 = __builtin_amdgcn_mfma_f32_16x16x32_bf16(w3, X0, b1c[3], 0, 0, 0);

        // ---- frag group 1 (fids 4..7) from LDS, then 4 MFMAs on X1 ----
        asm volatile("ds_read_b128 %0, %1 offset:4096" : "=v"(w0) : "v"(waddr));
        asm volatile("ds_read_b128 %0, %1 offset:5120" : "=v"(w1) : "v"(waddr));
        asm volatile("ds_read_b128 %0, %1 offset:6144" : "=v"(w2) : "v"(waddr));
        asm volatile("ds_read_b128 %0, %1 offset:7168" : "=v"(w3) : "v"(waddr));
        asm volatile("s_waitcnt lgkmcnt(0)" ::: "memory");
        __builtin_amdgcn_sched_barrier(0);

        a0 = __builtin_amdgcn_mfma_f32_16x16x32_bf16(w0, X1, a0, 0, 0, 0);
        a1 = __builtin_amdgcn_mfma_f32_16x16x32_bf16(w1, X1, a1, 0, 0, 0);
        a2 = __builtin_amdgcn_mfma_f32_16x16x32_bf16(w2, X1, a2, 0, 0, 0);
        a3 = __builtin_amdgcn_mfma_f32_16x16x32_bf16(w3, X1, a3, 0, 0, 0);

        // epilogue: e = sum_j tanh(H[atom][j]) * W2[j], fully in-lane
        float ev;
        ev  = fast_tanh(a0[0]) * w2c[0][0];
        ev += fast_tanh(a0[1]) * w2c[0][1];
        ev += fast_tanh(a0[2]) * w2c[0][2];
        ev += fast_tanh(a0[3]) * w2c[0][3];
        ev += fast_tanh(a1[0]) * w2c[1][0];
        ev += fast_tanh(a1[1]) * w2c[1][1];
        ev += fast_tanh(a1[2]) * w2c[1][2];
        ev += fast_tanh(a1[3]) * w2c[1][3];
        ev += fast_tanh(a2[0]) * w2c[2][0];
        ev += fast_tanh(a2[1]) * w2c[2][1];
        ev += fast_tanh(a2[2]) * w2c[2][2];
        ev += fast_tanh(a2[3]) * w2c[2][3];
        ev += fast_tanh(a3[0]) * w2c[3][0];
        ev += fast_tanh(a3[1]) * w2c[3][1];
        ev += fast_tanh(a3[2]) * w2c[3][2];
        ev += fast_tanh(a3[3]) * w2c[3][3];
        ev += __shfl_xor(ev, 16);
        ev += __shfl_xor(ev, 32);

        if (lane < 16) atomicAdd(&out[ia], ev + b2v);
    }
}

extern "C" void kernel_launch(void* const* d_in, const int* in_sizes, int n_in,
                              void* d_out, int out_size, void* d_ws, size_t ws_size,
                              hipStream_t stream) {
    Params p;
    for (int e = 0; e < 3; ++e) {
        p.e[e].x   = (const float*)d_in[6 * e + 0];
        p.e[e].idx = (const int*)  d_in[6 * e + 1];
        p.e[e].W1  = (const float*)d_in[6 * e + 2];
        p.e[e].b1  = (const float*)d_in[6 * e + 3];
        p.e[e].W2  = (const float*)d_in[6 * e + 4];
        p.e[e].b2  = (const float*)d_in[6 * e + 5];
    }
    const int n_atoms = in_sizes[0] / 64;
    p.n_tiles = n_atoms / 16;   // 62,500

    float* out = (float*)d_out;
    // d_out is poisoned (0xAA) before timing and NOT re-zeroed between replays.
    hipMemsetAsync(out, 0, (size_t)out_size * sizeof(float), stream);

    // 1) standalone rate of the exact x access pattern at max TLP
    dim3 pgrid(2048, 3);
    bw_probe<<<pgrid, 256, 0, stream>>>(p);

    // 2) the real computation (round-10 structure, best steady performer)
    dim3 grid(1024, 3);
    atom_mlp<<<grid, 256, 0, stream>>>(p, out);
}

// Round 16
// 277.593 us; speedup vs baseline: 1.0901x; 1.0701x over previous
//
#include <hip/hip_runtime.h>

// FullNN: per-atom MLP (FEAT=64 -> tanh(HID=64) -> 1) + segment-sum over 32768 structs.
// Round 16: round-15's pure-read probe measured the x-stream's standalone platform
// rate: 185us (4.15 TB/s delivered, FETCH 381MB @ 2.06 TB/s) at 78% occupancy with
// ZERO compute -- the fused kernel (204us) is within 10% of the pattern floor.
// Last dial: the probe ran at 78% occupancy vs the fused kernel's 51%. Same kernel
// as round 10 (best steady performer, 44 VGPR) with __launch_bounds__(256,8)
// (VGPR cap 64 > 44 live) to let 8 waves/SIMD reside. If this doesn't close the
// gap, the kernel is at the measured roofline for this access shape.
//
// MFMA mfma_f32_16x16x32_bf16, swapped H^T = W1^T @ x^T (learn_hip m89/m97):
//   A: row=lane&15, k=(lane>>4)*8+i -> W1^T frag (LDS, shared by 4 waves)
//   B: col=lane&15 (= atom), k=(lane>>4)*8+i -> x^T frag (registers)
//   D: col=lane&15 (= atom), j=16t+kg*4+r    -> in-lane W2 reduce, 2 shfls

typedef __attribute__((ext_vector_type(8))) short bf16x8;
typedef __attribute__((ext_vector_type(4))) float f32x4;

struct ElemPtrs {
    const float* x;
    const int*   idx;
    const float* W1;
    const float* b1;
    const float* W2;
    const float* b2;
};
struct Params {
    ElemPtrs e[3];
    int n_tiles;   // atoms / 16
};

__device__ __forceinline__ short f2bf(float f) {
    __bf16 h = (__bf16)f;           // hardware RNE; pairs into v_cvt_pk_bf16_f32
    return __builtin_bit_cast(short, h);
}

__device__ __forceinline__ float fast_tanh(float v) {
    v = __builtin_amdgcn_fmed3f(v, -10.0f, 10.0f);
    float t = __builtin_amdgcn_exp2f(v * 2.8853900817779268f); // 2^(2v*log2 e)
    return (t - 1.0f) * __builtin_amdgcn_rcpf(t + 1.0f);
}

__global__ __launch_bounds__(256, 8) void atom_mlp(Params p, float* __restrict__ out)
{
    const ElemPtrs ep = p.e[blockIdx.y];   // uniform index -> scalar code

    // W1^T fragments, shared by the block's 4 waves: [frag fid=s*4+t][lane] x 16B
    __shared__ bf16x8 Wlds[8][64];

    const int tid  = threadIdx.x;
    const int lane = tid & 63;
    const int col  = lane & 15;    // atom within tile
    const int kg   = lane >> 4;    // k-group

    // ---- cooperative stage of W1^T fragments ----
    {
        const int wv = tid >> 6;
        #pragma unroll
        for (int q = 0; q < 2; ++q) {
            const int fid = wv * 2 + q;
            const int s = fid >> 2, t = fid & 3;
            bf16x8 w;
            #pragma unroll
            for (int i = 0; i < 8; ++i)
                w[i] = f2bf(ep.W1[(s * 32 + kg * 8 + i) * 64 + 16 * t + col]);
            Wlds[fid][lane] = w;
        }
    }

    // per-lane b1 (MFMA C-init) and W2, j = 16t + kg*4 + r
    f32x4 b1c[4], w2c[4];
    #pragma unroll
    for (int t = 0; t < 4; ++t)
        #pragma unroll
        for (int r = 0; r < 4; ++r) {
            b1c[t][r] = ep.b1[16 * t + kg * 4 + r];
            w2c[t][r] = ep.W2[16 * t + kg * 4 + r];
        }
    const float b2v = ep.b2[0];

    __syncthreads();

    // 32-bit LDS byte address of this lane's frag 0 (frag fid at +fid*1024)
    typedef __attribute__((address_space(3))) const void* as3cv;
    const unsigned waddr = (unsigned)(size_t)(as3cv)&Wlds[0][lane];

    const int wid    = (blockIdx.x * 256 + tid) >> 6;
    const int nwaves = (gridDim.x * 256) >> 6;
    const size_t xoff = (size_t)col * 64 + (size_t)kg * 8;

    for (int tile = wid; tile < p.n_tiles; tile += nwaves) {
        const float* xp = ep.x + (size_t)tile * 1024 + xoff;
        const float4 c0 = *reinterpret_cast<const float4*>(xp);
        const float4 c1 = *reinterpret_cast<const float4*>(xp + 4);
        const float4 c2 = *reinterpret_cast<const float4*>(xp + 32);
        const float4 c3 = *reinterpret_cast<const float4*>(xp + 36);
        const int ia = ep.idx[tile * 16 + col];

        bf16x8 X0, X1;
        X0[0]=f2bf(c0.x); X0[1]=f2bf(c0.y); X0[2]=f2bf(c0.z); X0[3]=f2bf(c0.w);
        X0[4]=f2bf(c1.x); X0[5]=f2bf(c1.y); X0[6]=f2bf(c1.z); X0[7]=f2bf(c1.w);
        X1[0]=f2bf(c2.x); X1[1]=f2bf(c2.y); X1[2]=f2bf(c2.z); X1[3]=f2bf(c2.w);
        X1[4]=f2bf(c3.x); X1[5]=f2bf(c3.y); X1[6]=f2bf(c3.z); X1[7]=f2bf(c3.w);

        // ---- frag group 0 (fids 0..3) from LDS, then 4 MFMAs on X0 ----
        bf16x8 w0, w1, w2, w3;
        asm volatile("ds_read_b128 %0, %1 offset:0"    : "=v"(w0) : "v"(waddr));
        asm volatile("ds_read_b128 %0, %1 offset:1024" : "=v"(w1) : "v"(waddr));
        asm volatile("ds_read_b128 %0, %1 offset:2048" : "=v"(w2) : "v"(waddr));
        asm volatile("ds_read_b128 %0, %1 offset:3072" : "=v"(w3) : "v"(waddr));
        asm volatile("s_waitcnt lgkmcnt(0)" ::: "memory");
        __builtin_amdgcn_sched_barrier(0);

        f32x4 a0 = __builtin_amdgcn_mfma_f32_16x16x32_bf16(w0, X0, b1c[0], 0, 0, 0);
        f32x4 a1 = __builtin_amdgcn_mfma_f32_16x16x32_bf16(w1, X0, b1c[1], 0, 0, 0);
        f32x4 a2 = __builtin_amdgcn_mfma_f32_16x16x32_bf16(w2, X0, b1c[2], 0, 0, 0);
        f32x4 a3 = __builtin_amdgcn_mfma_f32_16x16x32_bf16(w3, X0, b1c[3], 0, 0, 0);

        // ---- frag group 1 (fids 4..7) from LDS, then 4 MFMAs on X1 ----
        asm volatile("ds_read_b128 %0, %1 offset:4096" : "=v"(w0) : "v"(waddr));
        asm volatile("ds_read_b128 %0, %1 offset:5120" : "=v"(w1) : "v"(waddr));
        asm volatile("ds_read_b128 %0, %1 offset:6144" : "=v"(w2) : "v"(waddr));
        asm volatile("ds_read_b128 %0, %1 offset:7168" : "=v"(w3) : "v"(waddr));
        asm volatile("s_waitcnt lgkmcnt(0)" ::: "memory");
        __builtin_amdgcn_sched_barrier(0);

        a0 = __builtin_amdgcn_mfma_f32_16x16x32_bf16(w0, X1, a0, 0, 0, 0);
        a1 = __builtin_amdgcn_mfma_f32_16x16x32_bf16(w1, X1, a1, 0, 0, 0);
        a2 = __builtin_amdgcn_mfma_f32_16x16x32_bf16(w2, X1, a2, 0, 0, 0);
        a3 = __builtin_amdgcn_mfma_f32_16x16x32_bf16(w3, X1, a3, 0, 0, 0);

        // epilogue: e = sum_j tanh(H[atom][j]) * W2[j], fully in-lane
        float ev;
        ev  = fast_tanh(a0[0]) * w2c[0][0];
        ev += fast_tanh(a0[1]) * w2c[0][1];
        ev += fast_tanh(a0[2]) * w2c[0][2];
        ev += fast_tanh(a0[3]) * w2c[0][3];
        ev += fast_tanh(a1[0]) * w2c[1][0];
        ev += fast_tanh(a1[1]) * w2c[1][1];
        ev += fast_tanh(a1[2]) * w2c[1][2];
        ev += fast_tanh(a1[3]) * w2c[1][3];
        ev += fast_tanh(a2[0]) * w2c[2][0];
        ev += fast_tanh(a2[1]) * w2c[2][1];
        ev += fast_tanh(a2[2]) * w2c[2][2];
        ev += fast_tanh(a2[3]) * w2c[2][3];
        ev += fast_tanh(a3[0]) * w2c[3][0];
        ev += fast_tanh(a3[1]) * w2c[3][1];
        ev += fast_tanh(a3[2]) * w2c[3][2];
        ev += fast_tanh(a3[3]) * w2c[3][3];
        ev += __shfl_xor(ev, 16);
        ev += __shfl_xor(ev, 32);

        if (lane < 16) atomicAdd(&out[ia], ev + b2v);
    }
}

extern "C" void kernel_launch(void* const* d_in, const int* in_sizes, int n_in,
                              void* d_out, int out_size, void* d_ws, size_t ws_size,
                              hipStream_t stream) {
    Params p;
    for (int e = 0; e < 3; ++e) {
        p.e[e].x   = (const float*)d_in[6 * e + 0];
        p.e[e].idx = (const int*)  d_in[6 * e + 1];
        p.e[e].W1  = (const float*)d_in[6 * e + 2];
        p.e[e].b1  = (const float*)d_in[6 * e + 3];
        p.e[e].W2  = (const float*)d_in[6 * e + 4];
        p.e[e].b2  = (const float*)d_in[6 * e + 5];
    }
    const int n_atoms = in_sizes[0] / 64;
    p.n_tiles = n_atoms / 16;   // 62,500

    float* out = (float*)d_out;
    // d_out is poisoned (0xAA) before timing and NOT re-zeroed between replays.
    hipMemsetAsync(out, 0, (size_t)out_size * sizeof(float), stream);

    // 1024x3 blocks; residency now allowed up to 8 blocks/CU (launch_bounds 8/EU).
    dim3 grid(1024, 3);
    atom_mlp<<<grid, 256, 0, stream>>>(p, out);
}

// Round 17
// 171.644 us; speedup vs baseline: 1.7629x; 1.6173x over previous
//
#include <hip/hip_runtime.h>

// FullNN: per-atom MLP (FEAT=64 -> tanh(HID=64) -> 1) + segment-sum over 32768 structs.
// Round 17: RESTORE the best-measured kernel (round-10 structure, verbatim).
// Round-16's (256,8) squeezed the allocator to 32 VGPR and spilled (WRITE 155MB,
// FETCH 821MB) -- reverting to (256,4).
//
// Evidence summary for the roofline claim (rounds 8-16):
//   - round-15 probe: the exact x access pattern, pure loads, 78% occupancy,
//     no compute: 185us = 4.15 TB/s delivered. This kernel: 204us = 91% of it.
//   - delivered BW is occupancy-invariant 20%-80% (rounds 10/13/15/16).
//   - nontemporal (R11), lane-linear+LDS redistribute (R14), global_load_lds (R9),
//     depth-1/2/3 pipelines (R4/12/13), atomic ablation (R8): all null/negative.
// Structural constraint: 768MB of x read once, atom-major 256B rows; platform
// delivers ~4.15 TB/s for this shape -> ~185us floor + ~10% fused compute.
//
// MFMA mfma_f32_16x16x32_bf16, swapped H^T = W1^T @ x^T (learn_hip m89/m97):
//   A: row=lane&15, k=(lane>>4)*8+i -> W1^T frag (LDS, shared by 4 waves)
//   B: col=lane&15 (= atom), k=(lane>>4)*8+i -> x^T frag (registers)
//   D: col=lane&15 (= atom), j=16t+kg*4+r    -> in-lane W2 reduce, 2 shfls

typedef __attribute__((ext_vector_type(8))) short bf16x8;
typedef __attribute__((ext_vector_type(4))) float f32x4;

struct ElemPtrs {
    const float* x;
    const int*   idx;
    const float* W1;
    const float* b1;
    const float* W2;
    const float* b2;
};
struct Params {
    ElemPtrs e[3];
    int n_tiles;   // atoms / 16
};

__device__ __forceinline__ short f2bf(float f) {
    __bf16 h = (__bf16)f;           // hardware RNE; pairs into v_cvt_pk_bf16_f32
    return __builtin_bit_cast(short, h);
}

__device__ __forceinline__ float fast_tanh(float v) {
    v = __builtin_amdgcn_fmed3f(v, -10.0f, 10.0f);
    float t = __builtin_amdgcn_exp2f(v * 2.8853900817779268f); // 2^(2v*log2 e)
    return (t - 1.0f) * __builtin_amdgcn_rcpf(t + 1.0f);
}

__global__ __launch_bounds__(256, 4) void atom_mlp(Params p, float* __restrict__ out)
{
    const ElemPtrs ep = p.e[blockIdx.y];   // uniform index -> scalar code

    // W1^T fragments, shared by the block's 4 waves: [frag fid=s*4+t][lane] x 16B
    __shared__ bf16x8 Wlds[8][64];

    const int tid  = threadIdx.x;
    const int lane = tid & 63;
    const int col  = lane & 15;    // atom within tile
    const int kg   = lane >> 4;    // k-group

    // ---- cooperative stage of W1^T fragments ----
    {
        const int wv = tid >> 6;
        #pragma unroll
        for (int q = 0; q < 2; ++q) {
            const int fid = wv * 2 + q;
            const int s = fid >> 2, t = fid & 3;
            bf16x8 w;
            #pragma unroll
            for (int i = 0; i < 8; ++i)
                w[i] = f2bf(ep.W1[(s * 32 + kg * 8 + i) * 64 + 16 * t + col]);
            Wlds[fid][lane] = w;
        }
    }

    // per-lane b1 (MFMA C-init) and W2, j = 16t + kg*4 + r
    f32x4 b1c[4], w2c[4];
    #pragma unroll
    for (int t = 0; t < 4; ++t)
        #pragma unroll
        for (int r = 0; r < 4; ++r) {
            b1c[t][r] = ep.b1[16 * t + kg * 4 + r];
            w2c[t][r] = ep.W2[16 * t + kg * 4 + r];
        }
    const float b2v = ep.b2[0];

    __syncthreads();

    // 32-bit LDS byte address of this lane's frag 0 (frag fid at +fid*1024)
    typedef __attribute__((address_space(3))) const void* as3cv;
    const unsigned waddr = (unsigned)(size_t)(as3cv)&Wlds[0][lane];

    const int wid    = (blockIdx.x * 256 + tid) >> 6;
    const int nwaves = (gridDim.x * 256) >> 6;
    const size_t xoff = (size_t)col * 64 + (size_t)kg * 8;

    for (int tile = wid; tile < p.n_tiles; tile += nwaves) {
        const float* xp = ep.x + (size_t)tile * 1024 + xoff;
        const float4 c0 = *reinterpret_cast<const float4*>(xp);
        const float4 c1 = *reinterpret_cast<const float4*>(xp + 4);
        const float4 c2 = *reinterpret_cast<const float4*>(xp + 32);
        const float4 c3 = *reinterpret_cast<const float4*>(xp + 36);
        const int ia = ep.idx[tile * 16 + col];

        bf16x8 X0, X1;
        X0[0]=f2bf(c0.x); X0[1]=f2bf(c0.y); X0[2]=f2bf(c0.z); X0[3]=f2bf(c0.w);
        X0[4]=f2bf(c1.x); X0[5]=f2bf(c1.y); X0[6]=f2bf(c1.z); X0[7]=f2bf(c1.w);
        X1[0]=f2bf(c2.x); X1[1]=f2bf(c2.y); X1[2]=f2bf(c2.z); X1[3]=f2bf(c2.w);
        X1[4]=f2bf(c3.x); X1[5]=f2bf(c3.y); X1[6]=f2bf(c3.z); X1[7]=f2bf(c3.w);

        // ---- frag group 0 (fids 0..3) from LDS, then 4 MFMAs on X0 ----
        bf16x8 w0, w1, w2, w3;
        asm volatile("ds_read_b128 %0, %1 offset:0"    : "=v"(w0) : "v"(waddr));
        asm volatile("ds_read_b128 %0, %1 offset:1024" : "=v"(w1) : "v"(waddr));
        asm volatile("ds_read_b128 %0, %1 offset:2048" : "=v"(w2) : "v"(waddr));
        asm volatile("ds_read_b128 %0, %1 offset:3072" : "=v"(w3) : "v"(waddr));
        asm volatile("s_waitcnt lgkmcnt(0)" ::: "memory");
        __builtin_amdgcn_sched_barrier(0);

        f32x4 a0 = __builtin_amdgcn_mfma_f32_16x16x32_bf16(w0, X0, b1c[0], 0, 0, 0);
        f32x4 a1 = __builtin_amdgcn_mfma_f32_16x16x32_bf16(w1, X0, b1c[1], 0, 0, 0);
        f32x4 a2 = __builtin_amdgcn_mfma_f32_16x16x32_bf16(w2, X0, b1c[2], 0, 0, 0);
        f32x4 a3 = __builtin_amdgcn_mfma_f32_16x16x32_bf16(w3, X0, b1c[3], 0, 0, 0);

        // ---- frag group 1 (fids 4..7) from LDS, then 4 MFMAs on X1 ----
        asm volatile("ds_read_b128 %0, %1 offset:4096" : "=v"(w0) : "v"(waddr));
        asm volatile("ds_read_b128 %0, %1 offset:5120" : "=v"(w1) : "v"(waddr));
        asm volatile("ds_read_b128 %0, %1 offset:6144" : "=v"(w2) : "v"(waddr));
        asm volatile("ds_read_b128 %0, %1 offset:7168" : "=v"(w3) : "v"(waddr));
        asm volatile("s_waitcnt lgkmcnt(0)" ::: "memory");
        __builtin_amdgcn_sched_barrier(0);

        a0 = __builtin_amdgcn_mfma_f32_16x16x32_bf16(w0, X1, a0, 0, 0, 0);
        a1 = __builtin_amdgcn_mfma_f32_16x16x32_bf16(w1, X1, a1, 0, 0, 0);
        a2 = __builtin_amdgcn_mfma_f32_16x16x32_bf16(w2, X1, a2, 0, 0, 0);
        a3 = __builtin_amdgcn_mfma_f32_16x16x32_bf16(w3, X1, a3, 0, 0, 0);

        // epilogue: e = sum_j tanh(H[atom][j]) * W2[j], fully in-lane
        float ev;
        ev  = fast_tanh(a0[0]) * w2c[0][0];
        ev += fast_tanh(a0[1]) * w2c[0][1];
        ev += fast_tanh(a0[2]) * w2c[0][2];
        ev += fast_tanh(a0[3]) * w2c[0][3];
        ev += fast_tanh(a1[0]) * w2c[1][0];
        ev += fast_tanh(a1[1]) * w2c[1][1];
        ev += fast_tanh(a1[2]) * w2c[1][2];
        ev += fast_tanh(a1[3]) * w2c[1][3];
        ev += fast_tanh(a2[0]) * w2c[2][0];
        ev += fast_tanh(a2[1]) * w2c[2][1];
        ev += fast_tanh(a2[2]) * w2c[2][2];
        ev += fast_tanh(a2[3]) * w2c[2][3];
        ev += fast_tanh(a3[0]) * w2c[3][0];
        ev += fast_tanh(a3[1]) * w2c[3][1];
        ev += fast_tanh(a3[2]) * w2c[3][2];
        ev += fast_tanh(a3[3]) * w2c[3][3];
        ev += __shfl_xor(ev, 16);
        ev += __shfl_xor(ev, 32);

        if (lane < 16) atomicAdd(&out[ia], ev + b2v);
    }
}

extern "C" void kernel_launch(void* const* d_in, const int* in_sizes, int n_in,
                              void* d_out, int out_size, void* d_ws, size_t ws_size,
                              hipStream_t stream) {
    Params p;
    for (int e = 0; e < 3; ++e) {
        p.e[e].x   = (const float*)d_in[6 * e + 0];
        p.e[e].idx = (const int*)  d_in[6 * e + 1];
        p.e[e].W1  = (const float*)d_in[6 * e + 2];
        p.e[e].b1  = (const float*)d_in[6 * e + 3];
        p.e[e].W2  = (const float*)d_in[6 * e + 4];
        p.e[e].b2  = (const float*)d_in[6 * e + 5];
    }
    const int n_atoms = in_sizes[0] / 64;
    p.n_tiles = n_atoms / 16;   // 62,500

    float* out = (float*)d_out;
    // d_out is poisoned (0xAA) before timing and NOT re-zeroed between replays.
    hipMemsetAsync(out, 0, (size_t)out_size * sizeof(float), stream);

    // 1024x3 blocks = 12 blocks/CU of grid; residency limited by VGPR/LDS.
    dim3 grid(1024, 3);
    atom_mlp<<<grid, 256, 0, stream>>>(p, out);
}